// Round 7
// baseline (573.085 us; speedup 1.0000x reference)
//
#include <hip/hip_runtime.h>
#include <hip/hip_bf16.h>

namespace {
constexpr int B   = 16;
constexpr int NS  = 1000;
constexpr int IN  = 128;
constexpr int OUT = 128;
constexpr int K   = 256;   // IN + OUT
constexpr int XHP = 260;   // padded xh row stride (floats)

__device__ __forceinline__ float fsigmoid(float x) {
  return 1.0f / (1.0f + __expf(-x));
}
__device__ __forceinline__ float ftanh(float x) {
  return 2.0f / (1.0f + __expf(-2.0f * x)) - 1.0f;
}

// One block = (stock n, column half h): all 4 gates, 64 of 128 output cols.
// 4 waves (1 per gate); lane = kc (4-way K split) x cl (16 col-groups of 4).
__global__ __launch_bounds__(256, 4) void lstm_kernel(
    const float* __restrict__ xt, const float* __restrict__ hidden,
    const float* __restrict__ ct_1,
    const float* __restrict__ Wi, const float* __restrict__ bi,
    const float* __restrict__ Wo, const float* __restrict__ bo,
    const float* __restrict__ Wf, const float* __restrict__ bfp,
    const float* __restrict__ Wc, const float* __restrict__ bc,
    float* __restrict__ out) {
  // Phase 1: xh[16][XHP] fp32 (16.6 KiB). Phase 2: gbuf[4][16][64] (16 KiB, unioned).
  __shared__ float smem[B * XHP];

  const int bid = blockIdx.x;
  const int n   = bid >> 1;       // stock
  const int h   = bid & 1;        // column half: cols h*64 .. h*64+63
  const int tid = threadIdx.x;

  // ---- stage xh = concat(xt[:, n, :], hidden[0, n, :]) into LDS ----
  #pragma unroll
  for (int r = 0; r < 2; ++r) {
    const int idx = tid + (r << 8);   // 0..511
    const int b = idx >> 5;           // 0..15
    const int j = (idx & 31) << 2;    // 0,4,...,124
    const float4 xv = *reinterpret_cast<const float4*>(
        xt + ((size_t)b * NS + n) * IN + j);
    *reinterpret_cast<float4*>(&smem[b * XHP + j]) = xv;
    const float4 hv = *reinterpret_cast<const float4*>(
        hidden + (size_t)n * OUT + j);
    *reinterpret_cast<float4*>(&smem[b * XHP + IN + j]) = hv;
  }
  __syncthreads();

  const int g  = tid >> 6;         // gate 0..3 (one wave per gate)
  const int kc = (tid >> 4) & 3;   // K quarter: rows s*16 + kc*4 .. +3
  const int cl = tid & 15;         // col group: cols h*64 + cl*4 .. +3

  const float* Wg = (g == 0) ? Wi : (g == 1) ? Wo : (g == 2) ? Wf : Wc;
  const float* bg = (g == 0) ? bi : (g == 1) ? bo : (g == 2) ? bfp : bc;
  const float* wp = Wg + (size_t)n * (K * OUT) + h * 64 + cl * 4;

  float acc[B][4];
  #pragma unroll
  for (int b = 0; b < B; ++b)
    #pragma unroll
    for (int c = 0; c < 4; ++c) acc[b][c] = 0.f;

  // Two rolling weight buffers, prefetch distance ~1.5 compute phases.
  // Each dwordx4: 4 kc-rows x 64 cols = 1 KB fully distinct per wave.
  float4 wa[4], wb[4];
  #pragma unroll
  for (int j = 0; j < 4; ++j)
    wa[j] = *reinterpret_cast<const float4*>(wp + (size_t)(kc * 4 + j) * OUT);
  #pragma unroll
  for (int j = 0; j < 4; ++j)
    wb[j] = *reinterpret_cast<const float4*>(wp + (size_t)(16 + kc * 4 + j) * OUT);

  #pragma unroll 2
  for (int s = 0; s < 16; s += 2) {
    // ---- phase A: compute step s with wa, then refill wa <- step s+2 ----
    #pragma unroll
    for (int b = 0; b < B; ++b) {
      const float4 x = *reinterpret_cast<const float4*>(
          &smem[b * XHP + (s << 4) + (kc << 2)]);  // broadcast, 4 addrs, conflict-free
      #pragma unroll
      for (int j = 0; j < 4; ++j) {
        const float xs = (&x.x)[j];
        acc[b][0] = fmaf(xs, (&wa[j].x)[0], acc[b][0]);
        acc[b][1] = fmaf(xs, (&wa[j].x)[1], acc[b][1]);
        acc[b][2] = fmaf(xs, (&wa[j].x)[2], acc[b][2]);
        acc[b][3] = fmaf(xs, (&wa[j].x)[3], acc[b][3]);
      }
    }
    const int sa = (s + 2 < 16) ? s + 2 : 0;  // tail wrap: redundant but valid
    #pragma unroll
    for (int j = 0; j < 4; ++j)
      wa[j] = *reinterpret_cast<const float4*>(
          wp + (size_t)(sa * 16 + kc * 4 + j) * OUT);

    // ---- phase B: compute step s+1 with wb, then refill wb <- step s+3 ----
    #pragma unroll
    for (int b = 0; b < B; ++b) {
      const float4 x = *reinterpret_cast<const float4*>(
          &smem[b * XHP + ((s + 1) << 4) + (kc << 2)]);
      #pragma unroll
      for (int j = 0; j < 4; ++j) {
        const float xs = (&x.x)[j];
        acc[b][0] = fmaf(xs, (&wb[j].x)[0], acc[b][0]);
        acc[b][1] = fmaf(xs, (&wb[j].x)[1], acc[b][1]);
        acc[b][2] = fmaf(xs, (&wb[j].x)[2], acc[b][2]);
        acc[b][3] = fmaf(xs, (&wb[j].x)[3], acc[b][3]);
      }
    }
    const int sb = (s + 3 < 16) ? s + 3 : 0;
    #pragma unroll
    for (int j = 0; j < 4; ++j)
      wb[j] = *reinterpret_cast<const float4*>(
          wp + (size_t)(sb * 16 + kc * 4 + j) * OUT);
  }

  // ---- reduce the 4 kc quarters: lanes l, l^16, l^32, l^48 all end with the sum ----
  #pragma unroll
  for (int b = 0; b < B; ++b)
    #pragma unroll
    for (int c = 0; c < 4; ++c) {
      acc[b][c] += __shfl_xor(acc[b][c], 16, 64);
      acc[b][c] += __shfl_xor(acc[b][c], 32, 64);
    }

  const float4 bv = *reinterpret_cast<const float4*>(
      bg + (size_t)n * OUT + h * 64 + cl * 4);

  __syncthreads();  // all xh reads done; repurpose smem as gbuf[4][16][64]
  if (kc == 0) {
    #pragma unroll
    for (int b = 0; b < B; ++b) {
      float4 v;
      v.x = acc[b][0] + bv.x; v.y = acc[b][1] + bv.y;
      v.z = acc[b][2] + bv.z; v.w = acc[b][3] + bv.w;
      *reinterpret_cast<float4*>(&smem[((g * B + b) << 6) + (cl << 2)]) = v;
    }
  }
  __syncthreads();

  // ---- combine gates, write ht and ct (fp32 outputs) ----
  const size_t nbase = (size_t)n * OUT;
  #pragma unroll
  for (int r = 0; r < 4; ++r) {
    const int p  = tid + (r << 8);   // 0..1023
    const int b  = p >> 6;           // 0..15
    const int ol = p & 63;           // 0..63
    const int o  = h * 64 + ol;
    const float gi = smem[((0 * B + b) << 6) + ol];
    const float go = smem[((1 * B + b) << 6) + ol];
    const float gf = smem[((2 * B + b) << 6) + ol];
    const float gc = smem[((3 * B + b) << 6) + ol];
    const float it = fsigmoid(gi);
    const float ot = fsigmoid(go);
    const float ft = fsigmoid(gf);
    const float ch = ftanh(gc);
    const float cp = ct_1[nbase + o];
    const float ct = ft * cp + it * ch;
    const float ht = ot * ftanh(ct);
    const size_t oidx = (size_t)b * ((size_t)NS * OUT) + nbase + o;
    out[oidx] = ht;                              // ht
    out[(size_t)B * NS * OUT + oidx] = ct;       // ct
  }
}
}  // namespace

extern "C" void kernel_launch(void* const* d_in, const int* in_sizes, int n_in,
                              void* d_out, int out_size, void* d_ws, size_t ws_size,
                              hipStream_t stream) {
  const float* xt     = (const float*)d_in[0];
  const float* hidden = (const float*)d_in[1];
  const float* ct_1   = (const float*)d_in[2];
  const float* Wi     = (const float*)d_in[3];
  const float* bi     = (const float*)d_in[4];
  const float* Wo     = (const float*)d_in[5];
  const float* bo     = (const float*)d_in[6];
  const float* Wf     = (const float*)d_in[7];
  const float* bf     = (const float*)d_in[8];
  const float* Wc     = (const float*)d_in[9];
  const float* bc     = (const float*)d_in[10];

  lstm_kernel<<<2 * NS, 256, 0, stream>>>(xt, hidden, ct_1, Wi, bi, Wo, bo,
                                          Wf, bf, Wc, bc,
                                          (float*)d_out);
}

// Round 8
// 114.753 us; speedup vs baseline: 4.9941x; 4.9941x over previous
//
#include <hip/hip_runtime.h>
#include <hip/hip_bf16.h>

namespace {
constexpr int B   = 16;
constexpr int NS  = 1000;
constexpr int IN  = 128;
constexpr int OUT = 128;
constexpr int K   = 256;   // IN + OUT

typedef __attribute__((ext_vector_type(8))) short short8;
typedef __attribute__((ext_vector_type(4))) float f32x4;

__device__ __forceinline__ float fsigmoid(float x) {
  return 1.0f / (1.0f + __expf(-x));
}
__device__ __forceinline__ float ftanh(float x) {
  return 2.0f / (1.0f + __expf(-2.0f * x)) - 1.0f;
}
// fp32 -> bf16 round-to-nearest-even (bit pattern)
__device__ __forceinline__ unsigned int f2bf(float f) {
  unsigned int u = __builtin_bit_cast(unsigned int, f);
  u += 0x7fffu + ((u >> 16) & 1u);
  return u >> 16;
}
__device__ __forceinline__ unsigned int pack2(float lo, float hi) {
  return f2bf(lo) | (f2bf(hi) << 16);
}

// LDS arena (bytes):
//  [0,8192)      xh bf16 [16 b][256 k], row stride 512B, byte-addr XOR ((row&7)<<4)
//  [8192,40960)  8 per-wave W slices (4KB each, wid*4096): col-major [64 col][32 k] bf16,
//                addr = col*64 + k*2, XOR ((col&7)<<4). Per-wave private -> no K-loop barriers.
//                Epilogue overlay: gbuf f32 [4 gate][16 b][128 col] (32KB).
__global__ __launch_bounds__(512, 2) void lstm_kernel(
    const float* __restrict__ xt, const float* __restrict__ hidden,
    const float* __restrict__ ct_1,
    const float* __restrict__ Wi, const float* __restrict__ bi,
    const float* __restrict__ Wo, const float* __restrict__ bo,
    const float* __restrict__ Wf, const float* __restrict__ bfp,
    const float* __restrict__ Wc, const float* __restrict__ bc,
    float* __restrict__ out) {
  __shared__ __align__(16) unsigned char smem[40960];

  const int n   = blockIdx.x;
  const int tid = threadIdx.x;

  // ---- stage xh = concat(xt[:,n,:], hidden[0,n,:]) as bf16, swizzled ----
  {
    const int b  = tid >> 5;        // 0..15
    const int s  = tid & 31;        // 16B segment: k0 = s*8
    const int k0 = s << 3;
    float v[8];
    if (k0 < IN) {
      const float4 a = *reinterpret_cast<const float4*>(xt + ((size_t)b * NS + n) * IN + k0);
      const float4 c = *reinterpret_cast<const float4*>(xt + ((size_t)b * NS + n) * IN + k0 + 4);
      v[0]=a.x; v[1]=a.y; v[2]=a.z; v[3]=a.w; v[4]=c.x; v[5]=c.y; v[6]=c.z; v[7]=c.w;
    } else {
      const float4 a = *reinterpret_cast<const float4*>(hidden + (size_t)n * OUT + (k0 - IN));
      const float4 c = *reinterpret_cast<const float4*>(hidden + (size_t)n * OUT + (k0 - IN) + 4);
      v[0]=a.x; v[1]=a.y; v[2]=a.z; v[3]=a.w; v[4]=c.x; v[5]=c.y; v[6]=c.z; v[7]=c.w;
    }
    uint4 pk;
    pk.x = pack2(v[0], v[1]); pk.y = pack2(v[2], v[3]);
    pk.z = pack2(v[4], v[5]); pk.w = pack2(v[6], v[7]);
    const int addr = ((b << 9) + (s << 4)) ^ ((b & 7) << 4);
    *reinterpret_cast<uint4*>(&smem[addr]) = pk;
  }
  __syncthreads();

  const int wid  = tid >> 6;   // 0..7
  const int g    = wid >> 1;   // gate
  const int half = wid & 1;    // column half (cols half*64 .. +63)
  const int l    = tid & 63;
  const int g2   = l >> 4;     // k-subgroup 0..3 (k = g2*8..+7 within 32-chunk)
  const int c16  = l & 15;

  const float* Wg = (g == 0) ? Wi : (g == 1) ? Wo : (g == 2) ? Wf : Wc;
  const float* bg = (g == 0) ? bi : (g == 1) ? bo : (g == 2) ? bfp : bc;
  const float* wgp = Wg + (size_t)n * (K * OUT) + half * 64 + l;  // col = half*64+l

  const int wsl = 8192 + (wid << 12);  // this wave's 4KB W slice
  f32x4 acc[4] = {f32x4{0,0,0,0}, f32x4{0,0,0,0}, f32x4{0,0,0,0}, f32x4{0,0,0,0}};

  #pragma unroll
  for (int c = 0; c < 8; ++c) {
    // load 32 rows x 64 cols fp32 chunk: 32 dword loads, 256B distinct/instr, all in flight
    float wr[8][4];
    #pragma unroll
    for (int i = 0; i < 8; ++i)
      #pragma unroll
      for (int j = 0; j < 4; ++j)
        wr[i][j] = wgp[(size_t)((c << 5) + (i << 2) + j) * OUT];
    // cvt + col-major LDS write: lane's col = l, rows 4i..4i+3 -> one b64 per group
    #pragma unroll
    for (int i = 0; i < 8; ++i) {
      uint2 pw;
      pw.x = pack2(wr[i][0], wr[i][1]);
      pw.y = pack2(wr[i][2], wr[i][3]);
      const int a = (wsl + (l << 6) + (i << 3)) ^ ((l & 7) << 4);
      *reinterpret_cast<uint2*>(&smem[a]) = pw;
    }
    // A fragment: row=c16, k = c*32 + g2*8 .. +7
    const int aaddr = ((c16 << 9) + (c << 6) + (g2 << 4)) ^ ((c16 & 7) << 4);
    const short8 af = *reinterpret_cast<const short8*>(&smem[aaddr]);
    // B fragments + MFMA over this wave's 4 n-tiles
    #pragma unroll
    for (int t = 0; t < 4; ++t) {
      const int col   = (t << 4) + c16;        // slice-local col 0..63
      const int baddr = (wsl + (col << 6) + (g2 << 4)) ^ ((col & 7) << 4);
      const short8 bf = *reinterpret_cast<const short8*>(&smem[baddr]);
      acc[t] = __builtin_amdgcn_mfma_f32_16x16x32_bf16(af, bf, acc[t], 0, 0, 0);
    }
  }

  // ---- all MFMA reads done; overlay gbuf over W slices ----
  __syncthreads();
  float* gb = reinterpret_cast<float*>(&smem[8192]);
  #pragma unroll
  for (int t = 0; t < 4; ++t) {
    const int colg = (half << 6) + (t << 4) + c16;       // global col 0..127
    const float bias = bg[(size_t)n * OUT + colg];
    #pragma unroll
    for (int r = 0; r < 4; ++r) {
      const int b = (g2 << 2) + r;                       // C/D: row=(lane>>4)*4+reg
      gb[g * 2048 + b * 128 + colg] = acc[t][r] + bias;
    }
  }
  __syncthreads();

  // ---- combine gates, write ht and ct (fp32 outputs) ----
  const size_t nbase = (size_t)n * OUT;
  #pragma unroll
  for (int r = 0; r < 4; ++r) {
    const int p = tid + (r << 9);   // 0..2047
    const int b = p >> 7;
    const int o = p & 127;
    const float gi = gb[0 * 2048 + b * 128 + o];
    const float go = gb[1 * 2048 + b * 128 + o];
    const float gf = gb[2 * 2048 + b * 128 + o];
    const float gc = gb[3 * 2048 + b * 128 + o];
    const float it = fsigmoid(gi);
    const float ot = fsigmoid(go);
    const float ft = fsigmoid(gf);
    const float ch = ftanh(gc);
    const float cp = ct_1[nbase + o];
    const float ct = ft * cp + it * ch;
    const float ht = ot * ftanh(ct);
    const size_t oidx = (size_t)b * ((size_t)NS * OUT) + nbase + o;
    out[oidx] = ht;                              // ht
    out[(size_t)B * NS * OUT + oidx] = ct;       // ct
  }
}
}  // namespace

extern "C" void kernel_launch(void* const* d_in, const int* in_sizes, int n_in,
                              void* d_out, int out_size, void* d_ws, size_t ws_size,
                              hipStream_t stream) {
  const float* xt     = (const float*)d_in[0];
  const float* hidden = (const float*)d_in[1];
  const float* ct_1   = (const float*)d_in[2];
  const float* Wi     = (const float*)d_in[3];
  const float* bi     = (const float*)d_in[4];
  const float* Wo     = (const float*)d_in[5];
  const float* bo     = (const float*)d_in[6];
  const float* Wf     = (const float*)d_in[7];
  const float* bf     = (const float*)d_in[8];
  const float* Wc     = (const float*)d_in[9];
  const float* bc     = (const float*)d_in[10];

  lstm_kernel<<<NS, 512, 0, stream>>>(xt, hidden, ct_1, Wi, bi, Wo, bo,
                                      Wf, bf, Wc, bc,
                                      (float*)d_out);
}

// Round 9
// 110.617 us; speedup vs baseline: 5.1808x; 1.0374x over previous
//
#include <hip/hip_runtime.h>
#include <hip/hip_bf16.h>

namespace {
constexpr int B   = 16;
constexpr int NS  = 1000;
constexpr int IN  = 128;
constexpr int OUT = 128;
constexpr int K   = 256;   // IN + OUT

typedef __attribute__((ext_vector_type(8))) short short8;
typedef __attribute__((ext_vector_type(4))) float f32x4;

__device__ __forceinline__ float fsigmoid(float x) {
  return 1.0f / (1.0f + __expf(-x));
}
__device__ __forceinline__ float ftanh(float x) {
  return 2.0f / (1.0f + __expf(-2.0f * x)) - 1.0f;
}
// fp32 -> bf16 round-to-nearest-even (bit pattern)
__device__ __forceinline__ unsigned int f2bf(float f) {
  unsigned int u = __builtin_bit_cast(unsigned int, f);
  u += 0x7fffu + ((u >> 16) & 1u);
  return u >> 16;
}
__device__ __forceinline__ unsigned int pack2(float lo, float hi) {
  return f2bf(lo) | (f2bf(hi) << 16);
}
// W slice: [4 kq][64 col][16B]; quad-swizzle spreads col across bank quads.
// Bank quad q = (col&7) ^ ((col>>3)&7): writes and reads both 2-way max (free).
__device__ __forceinline__ int slice_addr(int base, int kq, int col) {
  return base + (kq << 10) + ((col << 4) ^ (((col >> 3) & 7) << 4));
}

// LDS arena (bytes):
//  [0,8192)      xh bf16 [16 b][256 k], row stride 512B, byte XOR ((b&7)<<4)
//  [8192,40960)  8 per-wave W slices (4KB @ wid*4096), layout per slice_addr.
//  Epilogue overlay from 0: gbuf f32, idx = g*2064 + b*129 + col (33 KB).
__global__ __launch_bounds__(512, 2) void lstm_kernel(
    const float* __restrict__ xt, const float* __restrict__ hidden,
    const float* __restrict__ ct_1,
    const float* __restrict__ Wi, const float* __restrict__ bi,
    const float* __restrict__ Wo, const float* __restrict__ bo,
    const float* __restrict__ Wf, const float* __restrict__ bfp,
    const float* __restrict__ Wc, const float* __restrict__ bc,
    float* __restrict__ out) {
  __shared__ __align__(16) unsigned char smem[40960];

  const int n   = blockIdx.x;
  const int tid = threadIdx.x;

  // ---- stage xh = concat(xt[:,n,:], hidden[0,n,:]) as bf16, swizzled ----
  {
    const int b  = tid >> 5;        // 0..15
    const int s  = tid & 31;        // 16B segment: k0 = s*8
    const int k0 = s << 3;
    float v[8];
    if (k0 < IN) {
      const float4 a = *reinterpret_cast<const float4*>(xt + ((size_t)b * NS + n) * IN + k0);
      const float4 c = *reinterpret_cast<const float4*>(xt + ((size_t)b * NS + n) * IN + k0 + 4);
      v[0]=a.x; v[1]=a.y; v[2]=a.z; v[3]=a.w; v[4]=c.x; v[5]=c.y; v[6]=c.z; v[7]=c.w;
    } else {
      const float4 a = *reinterpret_cast<const float4*>(hidden + (size_t)n * OUT + (k0 - IN));
      const float4 c = *reinterpret_cast<const float4*>(hidden + (size_t)n * OUT + (k0 - IN) + 4);
      v[0]=a.x; v[1]=a.y; v[2]=a.z; v[3]=a.w; v[4]=c.x; v[5]=c.y; v[6]=c.z; v[7]=c.w;
    }
    uint4 pk;
    pk.x = pack2(v[0], v[1]); pk.y = pack2(v[2], v[3]);
    pk.z = pack2(v[4], v[5]); pk.w = pack2(v[6], v[7]);
    const int addr = ((b << 9) + (s << 4)) ^ ((b & 7) << 4);
    *reinterpret_cast<uint4*>(&smem[addr]) = pk;
  }
  __syncthreads();

  const int wid  = tid >> 6;   // 0..7
  const int g    = wid >> 1;   // gate
  const int half = wid & 1;    // column half (cols half*64 .. +63)
  const int l    = tid & 63;
  const int g2   = l >> 4;     // frag k-octet 0..3 / load row-octet rq
  const int c16  = l & 15;     // frag col 0..15 / load col-quad cl

  const float* Wg = (g == 0) ? Wi : (g == 1) ? Wo : (g == 2) ? Wf : Wc;
  const float* bg = (g == 0) ? bi : (g == 1) ? bo : (g == 2) ? bfp : bc;
  // lane's load base: cols half*64 + c16*4 .. +3 (dwordx4), rows g2*8 + i
  const float* wbase = Wg + (size_t)n * (K * OUT) + half * 64 + (c16 << 2);

  const int wsl = 8192 + (wid << 12);  // this wave's 4KB slice
  f32x4 acc[4] = {f32x4{0,0,0,0}, f32x4{0,0,0,0}, f32x4{0,0,0,0}, f32x4{0,0,0,0}};

  // ---- prologue: chunks 0 and 1 in registers (16 dwordx4 in flight) ----
  float4 wqa[8], wqb[8];
  #pragma unroll
  for (int i = 0; i < 8; ++i)
    wqa[i] = *reinterpret_cast<const float4*>(wbase + (size_t)((g2 << 3) + i) * OUT);
  #pragma unroll
  for (int i = 0; i < 8; ++i)
    wqb[i] = *reinterpret_cast<const float4*>(wbase + (size_t)(32 + (g2 << 3) + i) * OUT);

  #pragma unroll 1
  for (int c = 0; c < 8; c += 2) {
    // ======== chunk c (from wqa) ========
    {
      uint4 pk[4];
      #pragma unroll
      for (int j = 0; j < 4; ++j) {
        pk[j].x = pack2((&wqa[0].x)[j], (&wqa[1].x)[j]);
        pk[j].y = pack2((&wqa[2].x)[j], (&wqa[3].x)[j]);
        pk[j].z = pack2((&wqa[4].x)[j], (&wqa[5].x)[j]);
        pk[j].w = pack2((&wqa[6].x)[j], (&wqa[7].x)[j]);
      }
      const int cn = (c + 2 < 8) ? c + 2 : 0;  // tail wrap (redundant, valid)
      #pragma unroll
      for (int i = 0; i < 8; ++i)
        wqa[i] = *reinterpret_cast<const float4*>(
            wbase + (size_t)((cn << 5) + (g2 << 3) + i) * OUT);
      #pragma unroll
      for (int j = 0; j < 4; ++j)
        *reinterpret_cast<uint4*>(&smem[slice_addr(wsl, g2, (c16 << 2) + j)]) = pk[j];

      const int aaddr = ((c16 << 9) + (c << 6) + (g2 << 4)) ^ ((c16 & 7) << 4);
      const short8 af = *reinterpret_cast<const short8*>(&smem[aaddr]);
      #pragma unroll
      for (int t = 0; t < 4; ++t) {
        const short8 bfv = *reinterpret_cast<const short8*>(
            &smem[slice_addr(wsl, g2, (t << 4) + c16)]);
        acc[t] = __builtin_amdgcn_mfma_f32_16x16x32_bf16(af, bfv, acc[t], 0, 0, 0);
      }
    }
    // ======== chunk c+1 (from wqb) ========
    {
      uint4 pk[4];
      #pragma unroll
      for (int j = 0; j < 4; ++j) {
        pk[j].x = pack2((&wqb[0].x)[j], (&wqb[1].x)[j]);
        pk[j].y = pack2((&wqb[2].x)[j], (&wqb[3].x)[j]);
        pk[j].z = pack2((&wqb[4].x)[j], (&wqb[5].x)[j]);
        pk[j].w = pack2((&wqb[6].x)[j], (&wqb[7].x)[j]);
      }
      const int cn = (c + 3 < 8) ? c + 3 : 0;
      #pragma unroll
      for (int i = 0; i < 8; ++i)
        wqb[i] = *reinterpret_cast<const float4*>(
            wbase + (size_t)((cn << 5) + (g2 << 3) + i) * OUT);
      #pragma unroll
      for (int j = 0; j < 4; ++j)
        *reinterpret_cast<uint4*>(&smem[slice_addr(wsl, g2, (c16 << 2) + j)]) = pk[j];

      const int aaddr = ((c16 << 9) + ((c + 1) << 6) + (g2 << 4)) ^ ((c16 & 7) << 4);
      const short8 af = *reinterpret_cast<const short8*>(&smem[aaddr]);
      #pragma unroll
      for (int t = 0; t < 4; ++t) {
        const short8 bfv = *reinterpret_cast<const short8*>(
            &smem[slice_addr(wsl, g2, (t << 4) + c16)]);
        acc[t] = __builtin_amdgcn_mfma_f32_16x16x32_bf16(af, bfv, acc[t], 0, 0, 0);
      }
    }
  }

  // ---- epilogue: overlay gbuf (idx = g*2064 + b*129 + col) over whole arena ----
  __syncthreads();
  float* gb = reinterpret_cast<float*>(smem);
  #pragma unroll
  for (int t = 0; t < 4; ++t) {
    const int colg = (half << 6) + (t << 4) + c16;       // global col 0..127
    const float bias = bg[(size_t)n * OUT + colg];
    #pragma unroll
    for (int r = 0; r < 4; ++r) {
      const int b = (g2 << 2) + r;                       // C/D: row=(lane>>4)*4+reg
      gb[g * 2064 + b * 129 + colg] = acc[t][r] + bias;
    }
  }
  __syncthreads();

  // ---- combine gates, write ht and ct (fp32 outputs) ----
  const size_t nbase = (size_t)n * OUT;
  #pragma unroll
  for (int r = 0; r < 4; ++r) {
    const int p = tid + (r << 9);   // 0..2047
    const int b = p >> 7;
    const int o = p & 127;
    const float gi = gb[0 * 2064 + b * 129 + o];
    const float go = gb[1 * 2064 + b * 129 + o];
    const float gf = gb[2 * 2064 + b * 129 + o];
    const float gc = gb[3 * 2064 + b * 129 + o];
    const float it = fsigmoid(gi);
    const float ot = fsigmoid(go);
    const float ft = fsigmoid(gf);
    const float ch = ftanh(gc);
    const float cp = ct_1[nbase + o];
    const float ct = ft * cp + it * ch;
    const float ht = ot * ftanh(ct);
    const size_t oidx = (size_t)b * ((size_t)NS * OUT) + nbase + o;
    out[oidx] = ht;                              // ht
    out[(size_t)B * NS * OUT + oidx] = ct;       // ct
  }
}
}  // namespace

extern "C" void kernel_launch(void* const* d_in, const int* in_sizes, int n_in,
                              void* d_out, int out_size, void* d_ws, size_t ws_size,
                              hipStream_t stream) {
  const float* xt     = (const float*)d_in[0];
  const float* hidden = (const float*)d_in[1];
  const float* ct_1   = (const float*)d_in[2];
  const float* Wi     = (const float*)d_in[3];
  const float* bi     = (const float*)d_in[4];
  const float* Wo     = (const float*)d_in[5];
  const float* bo     = (const float*)d_in[6];
  const float* Wf     = (const float*)d_in[7];
  const float* bf     = (const float*)d_in[8];
  const float* Wc     = (const float*)d_in[9];
  const float* bc     = (const float*)d_in[10];

  lstm_kernel<<<NS, 512, 0, stream>>>(xt, hidden, ct_1, Wi, bi, Wo, bo,
                                      Wf, bf, Wc, bc,
                                      (float*)d_out);
}